// Round 12
// baseline (2674.510 us; speedup 1.0000x reference)
//
#include <hip/hip_runtime.h>

namespace {
constexpr int NB = 16;    // batch
constexpr int NP = 50;    // P nodes
constexpr int NM = 512;   // M
constexpr int NN = 1024;  // N
constexpr int NK = 20;    // scan steps
constexpr long ASZ = (long)NP * NM * NN;   // 26,214,400
constexpr long YSZ = (long)NB * NP * NN;   // 819,200
}

typedef __attribute__((ext_vector_type(8))) short bf16x8;
typedef __attribute__((ext_vector_type(4))) float f32x4;

__device__ __forceinline__ float lrelu(float x){ return x > 0.f ? x : 0.01f*x; }
__device__ __forceinline__ float bfu(unsigned short x){
  unsigned v = ((unsigned)x) << 16;
  return __builtin_bit_cast(float, v);
}
__device__ __forceinline__ unsigned short f2bf(float f){   // RNE f32->bf16
  unsigned u = __builtin_bit_cast(unsigned, f);
  u += 0x7fffu + ((u >> 16) & 1u);
  return (unsigned short)(u >> 16);
}
// tiled AtA element offset: [ntile=n>>4][ks=k>>5][lr=n&15][kg=(k>>3)&3][e=k&7]
__device__ __forceinline__ long toff(int n, int kk){
  return (long)(n>>4)*16384 + (long)(kk>>5)*512 + (long)((n&15)*32 + ((kk>>3)&3)*8 + (kk&7));
}

// ---------------- A (f32) -> abfT (transposed bf16 [p][n][m]) ----------------
__global__ __launch_bounds__(256) void k_prep(const float* __restrict__ A,
                      unsigned short* __restrict__ abfT){
  const int p = blockIdx.x, mt = blockIdx.y, nt = blockIdx.z;
  const int tid = threadIdx.x;
  __shared__ unsigned short tile[64][72];
  const int m0 = mt*64, n0 = nt*64;
  {
    int r = tid>>2, cs = (tid&3)*16;
    const float* src = A + ((long)p*NM + m0 + r)*NN + n0 + cs;
    unsigned short tmp[16];
    #pragma unroll
    for (int q=0;q<16;q+=4){
      float4 v = *(const float4*)(src+q);
      tmp[q+0]=f2bf(v.x); tmp[q+1]=f2bf(v.y); tmp[q+2]=f2bf(v.z); tmp[q+3]=f2bf(v.w);
    }
    #pragma unroll
    for (int q=0;q<16;q++) tile[r][cs+q] = tmp[q];
  }
  __syncthreads();
  {
    int r = tid>>2, cs = (tid&3)*16;   // r = n-offset, cs = m-offset
    unsigned short* dst = abfT + ((long)p*NN + n0 + r)*NM + m0 + cs;
    unsigned short tmp[16];
    #pragma unroll
    for (int q=0;q<16;q++) tmp[q] = tile[cs+q][r];
    #pragma unroll
    for (int q=0;q<16;q+=8) *(uint4*)(dst+q) = *(const uint4*)&tmp[q];
  }
}

// ---------------- scan-state init: y, ybf ----------------
__global__ void k_init(const float* __restrict__ y0, float* __restrict__ y,
                       unsigned short* __restrict__ ybf, int n){
  int e = (blockIdx.x*blockDim.x + threadIdx.x)*4;
  if (e >= n) return;
  float4 a = *(const float4*)(y0+e);
  *(float4*)(y+e) = a;
  ushort4 o; o.x=f2bf(a.x); o.y=f2bf(a.y); o.z=f2bf(a.z); o.w=f2bf(a.w);
  *(ushort4*)(ybf+e) = o;
}

// ---------------- w0 = u0*snb - atb ----------------
__global__ __launch_bounds__(256) void k_w0(const float* __restrict__ u0,
      const float* __restrict__ atb, const float* __restrict__ snbg,
      float* __restrict__ w){
  long i = ((long)blockIdx.x*256 + threadIdx.x)*4;
  if (i >= YSZ) return;
  long bp = i >> 10;          // b*NP+p
  int b = (int)(bp/NP), p = (int)(bp%NP);
  float sp = snbg[b*NP+p];
  float4 uv = *(const float4*)(u0+i);
  float4 av = *(const float4*)(atb+i);
  float4 wv;
  wv.x = uv.x*sp - av.x; wv.y = uv.y*sp - av.y;
  wv.z = uv.z*sp - av.z; wv.w = uv.w*sp - av.w;
  *(float4*)(w+i) = wv;
}

// ---------------- Atb: atb[b,p,n] = sum_m A[p,m,n]*b[b,p,m] (f32 src) ----------------
__global__ __launch_bounds__(256) void k_atb(const unsigned short* __restrict__ abfT,
                      const float* __restrict__ src, float* __restrict__ z){
  const int p = blockIdx.x;
  const int tid = threadIdx.x, wave = tid>>6, lane = tid&63;
  __shared__ unsigned short tlds[16][520];
  {
    int b = tid>>4, c0 = (tid&15)*8;
    const float* tr = src + ((long)b*NP + p)*NM;
    #pragma unroll
    for (int it=0; it<4; it++){
      float4 lo = *(const float4*)(tr + it*128 + c0);
      float4 hi = *(const float4*)(tr + it*128 + c0 + 4);
      unsigned short w[8];
      w[0]=f2bf(lo.x); w[1]=f2bf(lo.y); w[2]=f2bf(lo.z); w[3]=f2bf(lo.w);
      w[4]=f2bf(hi.x); w[5]=f2bf(hi.y); w[6]=f2bf(hi.z); w[7]=f2bf(hi.w);
      *(uint4*)&tlds[b][it*128 + c0] = *(const uint4*)w;
    }
  }
  __syncthreads();
  const int lr = lane&15, kg = lane>>4;
  const int nt0 = blockIdx.y*4 + wave;
  const int n0 = nt0*16, n1 = (nt0+32)*16;
  const unsigned short* b0 = abfT + ((long)p*NN + n0 + lr)*NM + kg*8;
  const unsigned short* b1 = abfT + ((long)p*NN + n1 + lr)*NM + kg*8;
  const unsigned short* tp = &tlds[lr][kg*8];
  f32x4 acc0a={0.f,0.f,0.f,0.f}, acc0b={0.f,0.f,0.f,0.f};
  f32x4 acc1a={0.f,0.f,0.f,0.f}, acc1b={0.f,0.f,0.f,0.f};
  #pragma unroll 4
  for (int ks=0; ks<16; ks+=2){
    bf16x8 t0 = *(const bf16x8*)(tp + ks*32);
    bf16x8 t1 = *(const bf16x8*)(tp + ks*32 + 32);
    bf16x8 b00 = *(const bf16x8*)(b0 + (long)ks*32);
    bf16x8 b01 = *(const bf16x8*)(b0 + (long)ks*32 + 32);
    bf16x8 b10 = *(const bf16x8*)(b1 + (long)ks*32);
    bf16x8 b11 = *(const bf16x8*)(b1 + (long)ks*32 + 32);
    acc0a = __builtin_amdgcn_mfma_f32_16x16x32_bf16(t0, b00, acc0a, 0, 0, 0);
    acc1a = __builtin_amdgcn_mfma_f32_16x16x32_bf16(t0, b10, acc1a, 0, 0, 0);
    acc0b = __builtin_amdgcn_mfma_f32_16x16x32_bf16(t1, b01, acc0b, 0, 0, 0);
    acc1b = __builtin_amdgcn_mfma_f32_16x16x32_bf16(t1, b11, acc1b, 0, 0, 0);
  }
  f32x4 acc0 = acc0a + acc0b;
  f32x4 acc1 = acc1a + acc1b;
  #pragma unroll
  for (int r=0;r<4;r++){
    int bb = kg*4 + r;
    z[((long)bb*NP + p)*NN + n0 + lr] = acc0[r];
    z[((long)bb*NP + p)*NN + n1 + lr] = acc1[r];
  }
}

// ---------------- AtA[p] (1024x1024, K=512), bf16 out in TILED layout ----------------
__global__ __launch_bounds__(256) void k_ata(const unsigned short* __restrict__ abfT,
                      unsigned short* __restrict__ ata){
  const int p = blockIdx.y;
  int yy = blockIdx.x, bi = 0;
  while (yy >= 8 - bi){ yy -= 8 - bi; bi++; }
  const int bj = bi + yy;
  const int i0 = bi*128, j0 = bj*128;
  const int tid = threadIdx.x, wave = tid>>6, lane = tid&63;
  const int lr = lane&15, kg = lane>>4;
  __shared__ unsigned short pa[128][72];
  __shared__ unsigned short pb[128][72];
  f32x4 acc[2][8];
  #pragma unroll
  for (int ti=0;ti<2;ti++)
    #pragma unroll
    for (int tj=0;tj<8;tj++) acc[ti][tj] = (f32x4){0.f,0.f,0.f,0.f};
  const unsigned short* Abase = abfT + (long)p*NN*NM;
  for (int mc=0; mc<NM; mc+=64){
    __syncthreads();
    {
      int r = tid>>1, c0 = (tid&1)*32;
      const unsigned short* sa = Abase + (long)(i0 + r)*NM + mc + c0;
      const unsigned short* sb = Abase + (long)(j0 + r)*NM + mc + c0;
      #pragma unroll
      for (int q=0;q<32;q+=8){
        *(uint4*)&pa[r][c0+q] = *(const uint4*)(sa+q);
        *(uint4*)&pb[r][c0+q] = *(const uint4*)(sb+q);
      }
    }
    __syncthreads();
    #pragma unroll
    for (int ks=0; ks<2; ks++){
      bf16x8 av0 = *(const bf16x8*)&pa[wave*32      + lr][ks*32 + kg*8];
      bf16x8 av1 = *(const bf16x8*)&pa[wave*32 + 16 + lr][ks*32 + kg*8];
      #pragma unroll
      for (int tj=0;tj<8;tj++){
        bf16x8 bv = *(const bf16x8*)&pb[tj*16 + lr][ks*32 + kg*8];
        acc[0][tj] = __builtin_amdgcn_mfma_f32_16x16x32_bf16(av0, bv, acc[0][tj], 0,0,0);
        acc[1][tj] = __builtin_amdgcn_mfma_f32_16x16x32_bf16(av1, bv, acc[1][tj], 0,0,0);
      }
    }
  }
  const long pbase = (long)p << 20;
  #pragma unroll
  for (int ti=0; ti<2; ti++){
    const int ib = i0 + wave*32 + ti*16;
    #pragma unroll
    for (int tj=0; tj<8; tj++){
      const int jb = j0 + tj*16;
      unsigned short w[4];
      #pragma unroll
      for (int r=0;r<4;r++) w[r] = f2bf(acc[ti][tj][r]);
      #pragma unroll
      for (int r=0;r<4;r++)
        ata[pbase + toff(ib + kg*4 + r, jb + lr)] = w[r];
      if (bi != bj){
        #pragma unroll
        for (int r=0;r<4;r++)
          ata[pbase + toff(jb + lr, ib + kg*4 + r)] = w[r];
      }
    }
  }
}

// ---------------- encoder GEMM: float4 W stream, acc[16] float4 ----------------
__global__ __launch_bounds__(256) void k_enc2(const float* __restrict__ X, const float* __restrict__ W,
                           float* __restrict__ part, int fi, int fo, int ichunk, int actin){
  const int tid = threadIdx.x;
  const int o0 = (blockIdx.x*256 + tid)*4;
  const int c  = blockIdx.y;
  const bool ok = o0 < fo;   // fo multiple of 4
  __shared__ float xs[64][16];
  float4 acc[16];
  #pragma unroll
  for (int b=0;b<16;b++){ acc[b].x=0.f; acc[b].y=0.f; acc[b].z=0.f; acc[b].w=0.f; }
  const long ibase = (long)c*ichunk;
  const int xb = tid&15, xio = (tid>>4)*4;
  for (int s=0; s<ichunk; s+=64){
    float4 v = *(const float4*)(X + (long)xb*fi + ibase + s + xio);
    if (actin){ v.x=lrelu(v.x); v.y=lrelu(v.y); v.z=lrelu(v.z); v.w=lrelu(v.w); }
    __syncthreads();
    xs[xio+0][xb]=v.x; xs[xio+1][xb]=v.y; xs[xio+2][xb]=v.z; xs[xio+3][xb]=v.w;
    __syncthreads();
    const float* wp = W + (ibase+s)*fo + o0;
    #pragma unroll 4
    for (int i=0;i<64;i++){
      float4 w;
      if (ok) w = *(const float4*)(wp + (long)i*fo);
      else { w.x=0.f; w.y=0.f; w.z=0.f; w.w=0.f; }
      #pragma unroll
      for (int b2=0;b2<16;b2+=4){
        float4 x4 = *(const float4*)&xs[i][b2];
        acc[b2+0].x += w.x*x4.x; acc[b2+0].y += w.y*x4.x; acc[b2+0].z += w.z*x4.x; acc[b2+0].w += w.w*x4.x;
        acc[b2+1].x += w.x*x4.y; acc[b2+1].y += w.y*x4.y; acc[b2+1].z += w.z*x4.y; acc[b2+1].w += w.w*x4.y;
        acc[b2+2].x += w.x*x4.z; acc[b2+2].y += w.y*x4.z; acc[b2+2].z += w.z*x4.z; acc[b2+2].w += w.w*x4.z;
        acc[b2+3].x += w.x*x4.w; acc[b2+3].y += w.y*x4.w; acc[b2+3].z += w.z*x4.w; acc[b2+3].w += w.w*x4.w;
      }
    }
  }
  if (ok){
    float* pp = part + ((long)c*16)*fo + o0;
    #pragma unroll
    for (int b=0;b<16;b++) *(float4*)(pp + (long)b*fo) = acc[b];
  }
}

__global__ void k_enc_reduce(const float* __restrict__ part, const float* __restrict__ bias,
                             float* __restrict__ out, int fo, int nchunk){
  int i = blockIdx.x*256 + threadIdx.x;
  if (i >= 16*fo) return;
  int o = i % fo;
  float s = bias[o];
  for (int c=0;c<nchunk;c++) s += part[(long)c*16*fo + i];
  out[i] = s;
}

// ---------------- per-batch graph matrices ----------------
__global__ __launch_bounds__(64) void k_graph(const int* __restrict__ ei, float* __restrict__ adjg,
                        float* __restrict__ dmg, float* __restrict__ snbg){
  const int b = blockIdx.x, tid = threadIdx.x;
  __shared__ float adj[2500], dm[2500], deg[50], dinv[50], snb[50];
  for (int i=tid;i<2500;i+=64){ adj[i]=0.f; dm[i]=0.f; }
  if (tid<50){ deg[tid]=0.f; snb[tid]=0.f; }
  __syncthreads();
  const int* e = ei + b*800;
  for (int k=tid;k<400;k+=64){
    atomicAdd(&deg[e[400+k]], 1.f);
    atomicAdd(&snb[e[k]], 1.f);
  }
  __syncthreads();
  if (tid<50) dinv[tid] = 1.f / sqrtf(deg[tid] + 1.f);
  __syncthreads();
  for (int k=tid;k<400;k+=64){
    int s = e[k], d = e[400+k];
    atomicAdd(&adj[d*50+s], dinv[s]*dinv[d]);
    atomicAdd(&dm[s*50+s],  1.f); atomicAdd(&dm[s*50+d], -1.f);
    atomicAdd(&dm[d*50+d],  1.f); atomicAdd(&dm[d*50+s], -1.f);
  }
  __syncthreads();
  if (tid<50) adj[tid*50+tid] += dinv[tid]*dinv[tid];
  __syncthreads();
  for (int i=tid;i<2500;i+=64){ adjg[b*2500+i]=adj[i]; dmg[b*2500+i]=dm[i]; }
  if (tid<50) snbg[b*50+tid]=snb[tid];
}

// ---------------- fused GCN x2 + head ----------------
__global__ __launch_bounds__(256) void k_gnn(const float* __restrict__ h3,
     const float* __restrict__ Wc1, const float* __restrict__ bc1,
     const float* __restrict__ Wc2, const float* __restrict__ bc2,
     const float* __restrict__ Wf1, const float* __restrict__ bf1,
     const float* __restrict__ Wf2, const float* __restrict__ bf2,
     const float* __restrict__ maxp, const float* __restrict__ adjg,
     float* __restrict__ hypg){
  const int b = blockIdx.x, tid = threadIdx.x;
  __shared__ float adj[2500];
  __shared__ float bufA[6400];
  __shared__ float bufB[6400];
  __shared__ float xm[128], hv1[64], raw[80];
  for (int i=tid;i<2500;i+=256) adj[i] = adjg[b*2500+i];

  const int j = tid & 127, nh = tid >> 7;
  float acc[25];
  #pragma unroll
  for (int q=0;q<25;q++) acc[q]=0.f;
  for (int ic=0; ic<4; ic++){
    __syncthreads();
    for (int e=tid; e<800; e+=256){
      int n = e>>4, seg = (e&15)*4;
      *(float4*)&bufB[n*64+seg] = *(const float4*)(h3 + (long)b*12800 + n*256 + ic*64 + seg);
    }
    __syncthreads();
    for (int i=0;i<64;i+=4){
      float w0 = Wc1[(long)(ic*64+i+0)*128 + j];
      float w1 = Wc1[(long)(ic*64+i+1)*128 + j];
      float w2 = Wc1[(long)(ic*64+i+2)*128 + j];
      float w3 = Wc1[(long)(ic*64+i+3)*128 + j];
      #pragma unroll
      for (int q=0;q<25;q++){
        float4 xv = *(const float4*)&bufB[(nh*25+q)*64 + i];
        acc[q] += xv.x*w0 + xv.y*w1 + xv.z*w2 + xv.w*w3;
      }
    }
  }
  __syncthreads();
  #pragma unroll
  for (int q=0;q<25;q++) bufA[(nh*25+q)*128 + j] = acc[q];
  __syncthreads();
  {
    float a2[25];
    float bv = bc1[j];
    #pragma unroll
    for (int q=0;q<25;q++) a2[q]=bv;
    for (int qq=0; qq<50; qq++){
      float hvv = bufA[qq*128 + j];
      #pragma unroll
      for (int q=0;q<25;q++) a2[q] += adj[(nh*25+q)*50 + qq]*hvv;
    }
    __syncthreads();
    #pragma unroll
    for (int q=0;q<25;q++) bufB[(nh*25+q)*128 + j] = lrelu(a2[q]);
  }
  __syncthreads();
  {
    float a2[25];
    #pragma unroll
    for (int q=0;q<25;q++) a2[q]=0.f;
    for (int i=0;i<128;i+=4){
      float w0 = Wc2[(long)(i+0)*128 + j];
      float w1 = Wc2[(long)(i+1)*128 + j];
      float w2 = Wc2[(long)(i+2)*128 + j];
      float w3 = Wc2[(long)(i+3)*128 + j];
      #pragma unroll
      for (int q=0;q<25;q++){
        float4 xv = *(const float4*)&bufB[(nh*25+q)*128 + i];
        a2[q] += xv.x*w0 + xv.y*w1 + xv.z*w2 + xv.w*w3;
      }
    }
    __syncthreads();
    #pragma unroll
    for (int q=0;q<25;q++) bufA[(nh*25+q)*128 + j] = a2[q];
  }
  __syncthreads();
  {
    float a2[25];
    float bv = bc2[j];
    #pragma unroll
    for (int q=0;q<25;q++) a2[q]=bv;
    for (int qq=0; qq<50; qq++){
      float hvv = bufA[qq*128 + j];
      #pragma unroll
      for (int q=0;q<25;q++) a2[q] += adj[(nh*25+q)*50 + qq]*hvv;
    }
    __syncthreads();
    #pragma unroll
    for (int q=0;q<25;q++) bufB[(nh*25+q)*128 + j] = lrelu(a2[q]);
  }
  __syncthreads();
  if (tid < 128){
    float s = 0.f;
    for (int n=0;n<50;n++) s += bufB[n*128 + tid];
    xm[tid] = s * (1.f/50.f);
  }
  __syncthreads();
  if (tid < 64){
    float s = bf1[tid];
    for (int i=0;i<128;i++) s += xm[i]*Wf1[i*64 + tid];
    hv1[tid] = lrelu(s);
  }
  __syncthreads();
  if (tid < 80){
    float s = bf2[tid];
    for (int i=0;i<64;i++) s += hv1[i]*Wf2[i*80 + tid];
    raw[tid] = s;
  }
  __syncthreads();
  if (tid < 4){
    float c = 0.f;
    for (int k=0;k<20;k++){
      c += raw[k*4 + tid];
      hypg[b*80 + k*4 + tid] = maxp[tid] / (1.f + expf(-c));
    }
  }
}

// ---------------- merged scan step: dlt = Dm@y_k, w update, z = AtA@y_k, y update ----------------
// grid (50,16): block = (p, 64-col n-group), all 16 b. ONE kernel per scan step.
__global__ __launch_bounds__(256, 2) void k_z2(const unsigned short* __restrict__ ata,
      const unsigned short* __restrict__ ybin, const float* __restrict__ d0,
      const float* __restrict__ dmg, const float* __restrict__ snbg,
      const float* __restrict__ hypg, int k,
      float* __restrict__ y, float* __restrict__ w,
      unsigned short* __restrict__ ybout, float* __restrict__ yout){
  const int p = blockIdx.x;
  const int ng = blockIdx.y;                  // 64-col group
  const int tid = threadIdx.x, wave = tid>>6, lane = tid&63;
  const int lr = lane&15, kg = lane>>4;
  __shared__ unsigned short ylds[16][1032];   // own-p y_k: [b][1024]
  __shared__ unsigned short ybq[16][16][66];  // cross-p chunk: [q'][b][64]
  __shared__ float dmp[16][52];
  __shared__ float snp[16];

  // stage dm row p (per b) + snb
  for (int e2=tid; e2<800; e2+=256){
    int b=e2/50, q=e2%50;
    dmp[b][q] = dmg[b*2500 + p*50 + q];
  }
  if (tid<16) snp[tid] = snbg[tid*NP + p];
  // stage own-p y rows for the MFMA
  {
    int b = tid>>4, c0 = (tid&15)*8;
    const unsigned short* yr = ybin + ((long)b*NP + p)*NN;
    #pragma unroll
    for (int it=0; it<8; it++)
      *(uint4*)&ylds[b][it*128 + c0] = *(const uint4*)(yr + it*128 + c0);
  }

  const int nl = wave*16 + lr;                // 0..63 within group
  float dlt[4] = {0.f,0.f,0.f,0.f};
  if (k == 0){
    #pragma unroll
    for (int r=0;r<4;r++)
      dlt[r] = d0[((long)(kg*4+r)*NP + p)*NN + ng*64 + nl];
  } else {
    for (int qc=0; qc<50; qc+=16){
      const int qn = (50-qc < 16) ? (50-qc) : 16;
      __syncthreads();
      for (int rr = tid>>3; rr < qn*16; rr += 32){
        int q = rr >> 4, b = rr & 15;
        int c8 = (tid&7)*8;
        const unsigned short* src = ybin + ((long)b*NP + (qc+q))*NN + ng*64 + c8;
        *(uint4*)&ybq[q][b][c8] = *(const uint4*)src;
      }
      __syncthreads();
      #pragma unroll
      for (int r=0;r<4;r++){
        int b = kg*4+r;
        float s = 0.f;
        for (int q=0;q<qn;q++)
          s += dmp[b][qc+q] * bfu(ybq[q][b][nl]);
        dlt[r] += s;
      }
    }
  }

  // MFMA: z[b][n] for wave's 16-n tile, K=1024 over own-p y
  const int t  = ng*4 + wave;                 // n-tile 0..63
  const int n0 = t*16;
  const unsigned short* bp = ata + ((long)p<<20) + (long)t*16384 + lr*32 + kg*8;
  const unsigned short* yp = &ylds[lr][kg*8];

  bf16x8 B[3][4];
  #pragma unroll
  for (int j=0;j<4;j++) B[0][j] = *(const bf16x8*)(bp + (0*4+j)*512);
  #pragma unroll
  for (int j=0;j<4;j++) B[1][j] = *(const bf16x8*)(bp + (1*4+j)*512);

  // preload epilogue operands
  float yv4[4], wv4[4];
  float4 hp4[4];
  float etap[4];
  #pragma unroll
  for (int r=0;r<4;r++){
    const int b = kg*4 + r;
    const long idx = ((long)b*NP + p)*NN + n0 + lr;
    yv4[r] = y[idx]; wv4[r] = w[idx];
    hp4[r] = *(const float4*)(hypg + b*80 + k*4);
    etap[r] = (k > 0) ? hypg[b*80 + (k-1)*4 + 3] : 0.f;
  }
  __syncthreads();

  f32x4 a0={0.f,0.f,0.f,0.f}, a1={0.f,0.f,0.f,0.f}, a2={0.f,0.f,0.f,0.f}, a3={0.f,0.f,0.f,0.f};
  #pragma unroll
  for (int i=0;i<8;i++){
    const int cur = i % 3;
    const int nxt = (i+2) % 3;
    if (i < 6){
      #pragma unroll
      for (int j=0;j<4;j++) B[nxt][j] = *(const bf16x8*)(bp + ((i+2)*4+j)*512);
    }
    bf16x8 q0 = *(const bf16x8*)(yp + (i*4+0)*32);
    bf16x8 q1 = *(const bf16x8*)(yp + (i*4+1)*32);
    bf16x8 q2 = *(const bf16x8*)(yp + (i*4+2)*32);
    bf16x8 q3 = *(const bf16x8*)(yp + (i*4+3)*32);
    a0 = __builtin_amdgcn_mfma_f32_16x16x32_bf16(q0, B[cur][0], a0, 0,0,0);
    a1 = __builtin_amdgcn_mfma_f32_16x16x32_bf16(q1, B[cur][1], a1, 0,0,0);
    a2 = __builtin_amdgcn_mfma_f32_16x16x32_bf16(q2, B[cur][2], a2, 0,0,0);
    a3 = __builtin_amdgcn_mfma_f32_16x16x32_bf16(q3, B[cur][3], a3, 0,0,0);
  }
  f32x4 z = (a0 + a1) + (a2 + a3);
  #pragma unroll
  for (int r=0;r<4;r++){
    const int b = kg*4 + r;
    const long idx = ((long)b*NP + p)*NN + n0 + lr;
    // w_k = w_{k-1} + dlt_k * eta_{k-1} * snb  (k>0); e = w_k + dlt_k * rho_k
    float wn = wv4[r] + dlt[r]*etap[r]*snp[b];
    if (k > 0) w[idx] = wn;
    float e = wn + dlt[r]*hp4[r].z;
    float yv = yv4[r];
    float g = z[r] + ((yv>0.f)?1.f:((yv<0.f)?-1.f:0.f))*hp4[r].y + e;
    float ynv = yv - hp4[r].x*g;
    y[idx] = ynv; ybout[idx] = f2bf(ynv); yout[(long)k*YSZ + idx] = ynv;
  }
}

extern "C" void kernel_launch(void* const* d_in, const int* in_sizes, int n_in,
                              void* d_out, int out_size, void* d_ws, size_t ws_size,
                              hipStream_t stream){
  (void)in_sizes; (void)n_in; (void)out_size; (void)ws_size;
  const float* bin = (const float*)d_in[0];
  const float* A   = (const float*)d_in[1];
  const int*   ei  = (const int*)d_in[2];
  const float* mxp = (const float*)d_in[3];
  const float* We1 = (const float*)d_in[4];  const float* be1 = (const float*)d_in[5];
  const float* We2 = (const float*)d_in[6];  const float* be2 = (const float*)d_in[7];
  const float* We3 = (const float*)d_in[8];  const float* be3 = (const float*)d_in[9];
  const float* Wc1 = (const float*)d_in[10]; const float* bc1 = (const float*)d_in[11];
  const float* Wc2 = (const float*)d_in[12]; const float* bc2 = (const float*)d_in[13];
  const float* Wf1 = (const float*)d_in[14]; const float* bf1 = (const float*)d_in[15];
  const float* Wf2 = (const float*)d_in[16]; const float* bf2 = (const float*)d_in[17];
  const float* y0  = (const float*)d_in[18];
  const float* u0  = (const float*)d_in[19];
  const float* dd0 = (const float*)d_in[20];
  float* out = (float*)d_out;

  char* cur = (char*)d_ws;
  auto alloc = [&](size_t bytes)->void*{
    void* pp = (void*)cur; cur += (bytes + 255) & ~(size_t)255; return pp;
  };
  unsigned short* abfT = (unsigned short*)alloc(ASZ*2);              // 52.4 MB
  unsigned short* ata  = (unsigned short*)alloc((size_t)NP*1024*1024*2);  // 104.9 MB (tiled)
  float* atb = (float*)alloc(YSZ*4);
  float* y   = (float*)alloc(YSZ*4);
  unsigned short* ybf0 = (unsigned short*)alloc(YSZ*2);
  unsigned short* ybf1 = (unsigned short*)alloc(YSZ*2);
  float* w   = (float*)alloc(YSZ*4);
  float* h1  = (float*)alloc((size_t)16*3200*4);
  float* h2  = (float*)alloc((size_t)16*6400*4);
  float* h3  = (float*)alloc((size_t)16*12800*4);
  float* adj = (float*)alloc((size_t)16*2500*4);
  float* dm  = (float*)alloc((size_t)16*2500*4);
  float* snb = (float*)alloc((size_t)16*50*4);
  float* hyp = (float*)alloc((size_t)16*80*4);
  float* part= (float*)alloc((size_t)84000000);   // max 100*16*12800*4 = 81.9 MB

  // ---- one-time prep ----
  k_prep<<<dim3(50,8,16), dim3(256), 0, stream>>>(A, abfT);
  k_init<<<dim3(800), dim3(256), 0, stream>>>(y0, y, ybf0, (int)YSZ);
  k_atb<<<dim3(50,8), dim3(256), 0, stream>>>(abfT, bin, atb);
  k_ata<<<dim3(36,50), dim3(256), 0, stream>>>(abfT, ata);

  // ---- encoder MLP ----
  k_enc2<<<dim3(4,200),  dim3(256), 0, stream>>>(bin, We1, part, 25600, 3200, 128, 0);
  k_enc_reduce<<<dim3(200), dim3(256), 0, stream>>>(part, be1, h1, 3200, 200);
  k_enc2<<<dim3(7,50),  dim3(256), 0, stream>>>(h1, We2, part, 3200, 6400, 64, 1);
  k_enc_reduce<<<dim3(400), dim3(256), 0, stream>>>(part, be2, h2, 6400, 50);
  k_enc2<<<dim3(13,100), dim3(256), 0, stream>>>(h2, We3, part, 6400, 12800, 64, 1);
  k_enc_reduce<<<dim3(800), dim3(256), 0, stream>>>(part, be3, h3, 12800, 100);

  // ---- graph + fused GNN/head ----
  k_graph<<<dim3(16), dim3(64), 0, stream>>>(ei, adj, dm, snb);
  k_gnn<<<dim3(16), dim3(256), 0, stream>>>(h3, Wc1, bc1, Wc2, bc2, Wf1, bf1, Wf2, bf2, mxp, adj, hyp);
  k_w0<<<dim3(800), dim3(256), 0, stream>>>(u0, atb, snb, w);

  // ---- scan: ONE kernel per step ----
  for (int k=0;k<NK;k++){
    const unsigned short* ybin = (k & 1) ? ybf1 : ybf0;
    unsigned short* ybout      = (k & 1) ? ybf0 : ybf1;
    k_z2<<<dim3(50,16), dim3(256), 0, stream>>>(ata, ybin, dd0, dm, snb, hyp, k,
                                                y, w, ybout, out);
  }
}

// Round 13
// 2127.988 us; speedup vs baseline: 1.2568x; 1.2568x over previous
//
#include <hip/hip_runtime.h>

namespace {
constexpr int NB = 16;    // batch
constexpr int NP = 50;    // P nodes
constexpr int NM = 512;   // M
constexpr int NN = 1024;  // N
constexpr int NK = 20;    // scan steps
constexpr long ASZ = (long)NP * NM * NN;   // 26,214,400
constexpr long YSZ = (long)NB * NP * NN;   // 819,200
}

typedef __attribute__((ext_vector_type(8))) short bf16x8;
typedef __attribute__((ext_vector_type(4))) float f32x4;

__device__ __forceinline__ float lrelu(float x){ return x > 0.f ? x : 0.01f*x; }
__device__ __forceinline__ float bfu(unsigned short x){
  unsigned v = ((unsigned)x) << 16;
  return __builtin_bit_cast(float, v);
}
__device__ __forceinline__ unsigned short f2bf(float f){   // RNE f32->bf16
  unsigned u = __builtin_bit_cast(unsigned, f);
  u += 0x7fffu + ((u >> 16) & 1u);
  return (unsigned short)(u >> 16);
}
// tiled AtA element offset: [ntile=n>>4][ks=k>>5][lr=n&15][kg=(k>>3)&3][e=k&7]
__device__ __forceinline__ long toff(int n, int kk){
  return (long)(n>>4)*16384 + (long)(kk>>5)*512 + (long)((n&15)*32 + ((kk>>3)&3)*8 + (kk&7));
}

// ---------------- zero the barrier flags ----------------
__global__ void k_zero(unsigned int* flags, int n){
  int i = blockIdx.x*256 + threadIdx.x;
  if (i < n) flags[i] = 0u;
}

// ---------------- A (f32) -> abfT (transposed bf16 [p][n][m]) ----------------
__global__ __launch_bounds__(256) void k_prep(const float* __restrict__ A,
                      unsigned short* __restrict__ abfT){
  const int p = blockIdx.x, mt = blockIdx.y, nt = blockIdx.z;
  const int tid = threadIdx.x;
  __shared__ unsigned short tile[64][72];
  const int m0 = mt*64, n0 = nt*64;
  {
    int r = tid>>2, cs = (tid&3)*16;
    const float* src = A + ((long)p*NM + m0 + r)*NN + n0 + cs;
    unsigned short tmp[16];
    #pragma unroll
    for (int q=0;q<16;q+=4){
      float4 v = *(const float4*)(src+q);
      tmp[q+0]=f2bf(v.x); tmp[q+1]=f2bf(v.y); tmp[q+2]=f2bf(v.z); tmp[q+3]=f2bf(v.w);
    }
    #pragma unroll
    for (int q=0;q<16;q++) tile[r][cs+q] = tmp[q];
  }
  __syncthreads();
  {
    int r = tid>>2, cs = (tid&3)*16;   // r = n-offset, cs = m-offset
    unsigned short* dst = abfT + ((long)p*NN + n0 + r)*NM + m0 + cs;
    unsigned short tmp[16];
    #pragma unroll
    for (int q=0;q<16;q++) tmp[q] = tile[cs+q][r];
    #pragma unroll
    for (int q=0;q<16;q+=8) *(uint4*)(dst+q) = *(const uint4*)&tmp[q];
  }
}

// ---------------- Atb: atb[b,p,n] = sum_m A[p,m,n]*b[b,p,m] (f32 src) ----------------
__global__ __launch_bounds__(256) void k_atb(const unsigned short* __restrict__ abfT,
                      const float* __restrict__ src, float* __restrict__ z){
  const int p = blockIdx.x;
  const int tid = threadIdx.x, wave = tid>>6, lane = tid&63;
  __shared__ unsigned short tlds[16][520];
  {
    int b = tid>>4, c0 = (tid&15)*8;
    const float* tr = src + ((long)b*NP + p)*NM;
    #pragma unroll
    for (int it=0; it<4; it++){
      float4 lo = *(const float4*)(tr + it*128 + c0);
      float4 hi = *(const float4*)(tr + it*128 + c0 + 4);
      unsigned short w[8];
      w[0]=f2bf(lo.x); w[1]=f2bf(lo.y); w[2]=f2bf(lo.z); w[3]=f2bf(lo.w);
      w[4]=f2bf(hi.x); w[5]=f2bf(hi.y); w[6]=f2bf(hi.z); w[7]=f2bf(hi.w);
      *(uint4*)&tlds[b][it*128 + c0] = *(const uint4*)w;
    }
  }
  __syncthreads();
  const int lr = lane&15, kg = lane>>4;
  const int nt0 = blockIdx.y*4 + wave;
  const int n0 = nt0*16, n1 = (nt0+32)*16;
  const unsigned short* b0 = abfT + ((long)p*NN + n0 + lr)*NM + kg*8;
  const unsigned short* b1 = abfT + ((long)p*NN + n1 + lr)*NM + kg*8;
  const unsigned short* tp = &tlds[lr][kg*8];
  f32x4 acc0a={0.f,0.f,0.f,0.f}, acc0b={0.f,0.f,0.f,0.f};
  f32x4 acc1a={0.f,0.f,0.f,0.f}, acc1b={0.f,0.f,0.f,0.f};
  #pragma unroll 4
  for (int ks=0; ks<16; ks+=2){
    bf16x8 t0 = *(const bf16x8*)(tp + ks*32);
    bf16x8 t1 = *(const bf16x8*)(tp + ks*32 + 32);
    bf16x8 b00 = *(const bf16x8*)(b0 + (long)ks*32);
    bf16x8 b01 = *(const bf16x8*)(b0 + (long)ks*32 + 32);
    bf16x8 b10 = *(const bf16x8*)(b1 + (long)ks*32);
    bf16x8 b11 = *(const bf16x8*)(b1 + (long)ks*32 + 32);
    acc0a = __builtin_amdgcn_mfma_f32_16x16x32_bf16(t0, b00, acc0a, 0, 0, 0);
    acc1a = __builtin_amdgcn_mfma_f32_16x16x32_bf16(t0, b10, acc1a, 0, 0, 0);
    acc0b = __builtin_amdgcn_mfma_f32_16x16x32_bf16(t1, b01, acc0b, 0, 0, 0);
    acc1b = __builtin_amdgcn_mfma_f32_16x16x32_bf16(t1, b11, acc1b, 0, 0, 0);
  }
  f32x4 acc0 = acc0a + acc0b;
  f32x4 acc1 = acc1a + acc1b;
  #pragma unroll
  for (int r=0;r<4;r++){
    int bb = kg*4 + r;
    z[((long)bb*NP + p)*NN + n0 + lr] = acc0[r];
    z[((long)bb*NP + p)*NN + n1 + lr] = acc1[r];
  }
}

// ---------------- AtA[p] (1024x1024, K=512), bf16 out in TILED layout ----------------
__global__ __launch_bounds__(256) void k_ata(const unsigned short* __restrict__ abfT,
                      unsigned short* __restrict__ ata){
  const int p = blockIdx.y;
  int yy = blockIdx.x, bi = 0;
  while (yy >= 8 - bi){ yy -= 8 - bi; bi++; }
  const int bj = bi + yy;
  const int i0 = bi*128, j0 = bj*128;
  const int tid = threadIdx.x, wave = tid>>6, lane = tid&63;
  const int lr = lane&15, kg = lane>>4;
  __shared__ unsigned short pa[128][72];
  __shared__ unsigned short pb[128][72];
  f32x4 acc[2][8];
  #pragma unroll
  for (int ti=0;ti<2;ti++)
    #pragma unroll
    for (int tj=0;tj<8;tj++) acc[ti][tj] = (f32x4){0.f,0.f,0.f,0.f};
  const unsigned short* Abase = abfT + (long)p*NN*NM;
  for (int mc=0; mc<NM; mc+=64){
    __syncthreads();
    {
      int r = tid>>1, c0 = (tid&1)*32;
      const unsigned short* sa = Abase + (long)(i0 + r)*NM + mc + c0;
      const unsigned short* sb = Abase + (long)(j0 + r)*NM + mc + c0;
      #pragma unroll
      for (int q=0;q<32;q+=8){
        *(uint4*)&pa[r][c0+q] = *(const uint4*)(sa+q);
        *(uint4*)&pb[r][c0+q] = *(const uint4*)(sb+q);
      }
    }
    __syncthreads();
    #pragma unroll
    for (int ks=0; ks<2; ks++){
      bf16x8 av0 = *(const bf16x8*)&pa[wave*32      + lr][ks*32 + kg*8];
      bf16x8 av1 = *(const bf16x8*)&pa[wave*32 + 16 + lr][ks*32 + kg*8];
      #pragma unroll
      for (int tj=0;tj<8;tj++){
        bf16x8 bv = *(const bf16x8*)&pb[tj*16 + lr][ks*32 + kg*8];
        acc[0][tj] = __builtin_amdgcn_mfma_f32_16x16x32_bf16(av0, bv, acc[0][tj], 0,0,0);
        acc[1][tj] = __builtin_amdgcn_mfma_f32_16x16x32_bf16(av1, bv, acc[1][tj], 0,0,0);
      }
    }
  }
  const long pbase = (long)p << 20;
  #pragma unroll
  for (int ti=0; ti<2; ti++){
    const int ib = i0 + wave*32 + ti*16;
    #pragma unroll
    for (int tj=0; tj<8; tj++){
      const int jb = j0 + tj*16;
      unsigned short w[4];
      #pragma unroll
      for (int r=0;r<4;r++) w[r] = f2bf(acc[ti][tj][r]);
      #pragma unroll
      for (int r=0;r<4;r++)
        ata[pbase + toff(ib + kg*4 + r, jb + lr)] = w[r];
      if (bi != bj){
        #pragma unroll
        for (int r=0;r<4;r++)
          ata[pbase + toff(jb + lr, ib + kg*4 + r)] = w[r];
      }
    }
  }
}

// ---------------- encoder GEMM: float4 W stream, acc[16] float4 ----------------
__global__ __launch_bounds__(256) void k_enc2(const float* __restrict__ X, const float* __restrict__ W,
                           float* __restrict__ part, int fi, int fo, int ichunk, int actin){
  const int tid = threadIdx.x;
  const int o0 = (blockIdx.x*256 + tid)*4;
  const int c  = blockIdx.y;
  const bool ok = o0 < fo;   // fo multiple of 4
  __shared__ float xs[64][16];
  float4 acc[16];
  #pragma unroll
  for (int b=0;b<16;b++){ acc[b].x=0.f; acc[b].y=0.f; acc[b].z=0.f; acc[b].w=0.f; }
  const long ibase = (long)c*ichunk;
  const int xb = tid&15, xio = (tid>>4)*4;
  for (int s=0; s<ichunk; s+=64){
    float4 v = *(const float4*)(X + (long)xb*fi + ibase + s + xio);
    if (actin){ v.x=lrelu(v.x); v.y=lrelu(v.y); v.z=lrelu(v.z); v.w=lrelu(v.w); }
    __syncthreads();
    xs[xio+0][xb]=v.x; xs[xio+1][xb]=v.y; xs[xio+2][xb]=v.z; xs[xio+3][xb]=v.w;
    __syncthreads();
    const float* wp = W + (ibase+s)*fo + o0;
    #pragma unroll 4
    for (int i=0;i<64;i++){
      float4 w;
      if (ok) w = *(const float4*)(wp + (long)i*fo);
      else { w.x=0.f; w.y=0.f; w.z=0.f; w.w=0.f; }
      #pragma unroll
      for (int b2=0;b2<16;b2+=4){
        float4 x4 = *(const float4*)&xs[i][b2];
        acc[b2+0].x += w.x*x4.x; acc[b2+0].y += w.y*x4.x; acc[b2+0].z += w.z*x4.x; acc[b2+0].w += w.w*x4.x;
        acc[b2+1].x += w.x*x4.y; acc[b2+1].y += w.y*x4.y; acc[b2+1].z += w.z*x4.y; acc[b2+1].w += w.w*x4.y;
        acc[b2+2].x += w.x*x4.z; acc[b2+2].y += w.y*x4.z; acc[b2+2].z += w.z*x4.z; acc[b2+2].w += w.w*x4.z;
        acc[b2+3].x += w.x*x4.w; acc[b2+3].y += w.y*x4.w; acc[b2+3].z += w.z*x4.w; acc[b2+3].w += w.w*x4.w;
      }
    }
  }
  if (ok){
    float* pp = part + ((long)c*16)*fo + o0;
    #pragma unroll
    for (int b=0;b<16;b++) *(float4*)(pp + (long)b*fo) = acc[b];
  }
}

__global__ void k_enc_reduce(const float* __restrict__ part, const float* __restrict__ bias,
                             float* __restrict__ out, int fo, int nchunk){
  int i = blockIdx.x*256 + threadIdx.x;
  if (i >= 16*fo) return;
  int o = i % fo;
  float s = bias[o];
  for (int c=0;c<nchunk;c++) s += part[(long)c*16*fo + i];
  out[i] = s;
}

// ---------------- per-batch graph matrices ----------------
__global__ __launch_bounds__(64) void k_graph(const int* __restrict__ ei, float* __restrict__ adjg,
                        float* __restrict__ dmg, float* __restrict__ snbg){
  const int b = blockIdx.x, tid = threadIdx.x;
  __shared__ float adj[2500], dm[2500], deg[50], dinv[50], snb[50];
  for (int i=tid;i<2500;i+=64){ adj[i]=0.f; dm[i]=0.f; }
  if (tid<50){ deg[tid]=0.f; snb[tid]=0.f; }
  __syncthreads();
  const int* e = ei + b*800;
  for (int k=tid;k<400;k+=64){
    atomicAdd(&deg[e[400+k]], 1.f);
    atomicAdd(&snb[e[k]], 1.f);
  }
  __syncthreads();
  if (tid<50) dinv[tid] = 1.f / sqrtf(deg[tid] + 1.f);
  __syncthreads();
  for (int k=tid;k<400;k+=64){
    int s = e[k], d = e[400+k];
    atomicAdd(&adj[d*50+s], dinv[s]*dinv[d]);
    atomicAdd(&dm[s*50+s],  1.f); atomicAdd(&dm[s*50+d], -1.f);
    atomicAdd(&dm[d*50+d],  1.f); atomicAdd(&dm[d*50+s], -1.f);
  }
  __syncthreads();
  if (tid<50) adj[tid*50+tid] += dinv[tid]*dinv[tid];
  __syncthreads();
  for (int i=tid;i<2500;i+=64){ adjg[b*2500+i]=adj[i]; dmg[b*2500+i]=dm[i]; }
  if (tid<50) snbg[b*50+tid]=snb[tid];
}

// ---------------- fused GCN x2 + head ----------------
__global__ __launch_bounds__(256) void k_gnn(const float* __restrict__ h3,
     const float* __restrict__ Wc1, const float* __restrict__ bc1,
     const float* __restrict__ Wc2, const float* __restrict__ bc2,
     const float* __restrict__ Wf1, const float* __restrict__ bf1,
     const float* __restrict__ Wf2, const float* __restrict__ bf2,
     const float* __restrict__ maxp, const float* __restrict__ adjg,
     float* __restrict__ hypg){
  const int b = blockIdx.x, tid = threadIdx.x;
  __shared__ float adj[2500];
  __shared__ float bufA[6400];
  __shared__ float bufB[6400];
  __shared__ float xm[128], hv1[64], raw[80];
  for (int i=tid;i<2500;i+=256) adj[i] = adjg[b*2500+i];

  const int j = tid & 127, nh = tid >> 7;
  float acc[25];
  #pragma unroll
  for (int q=0;q<25;q++) acc[q]=0.f;
  for (int ic=0; ic<4; ic++){
    __syncthreads();
    for (int e=tid; e<800; e+=256){
      int n = e>>4, seg = (e&15)*4;
      *(float4*)&bufB[n*64+seg] = *(const float4*)(h3 + (long)b*12800 + n*256 + ic*64 + seg);
    }
    __syncthreads();
    for (int i=0;i<64;i+=4){
      float w0 = Wc1[(long)(ic*64+i+0)*128 + j];
      float w1 = Wc1[(long)(ic*64+i+1)*128 + j];
      float w2 = Wc1[(long)(ic*64+i+2)*128 + j];
      float w3 = Wc1[(long)(ic*64+i+3)*128 + j];
      #pragma unroll
      for (int q=0;q<25;q++){
        float4 xv = *(const float4*)&bufB[(nh*25+q)*64 + i];
        acc[q] += xv.x*w0 + xv.y*w1 + xv.z*w2 + xv.w*w3;
      }
    }
  }
  __syncthreads();
  #pragma unroll
  for (int q=0;q<25;q++) bufA[(nh*25+q)*128 + j] = acc[q];
  __syncthreads();
  {
    float a2[25];
    float bv = bc1[j];
    #pragma unroll
    for (int q=0;q<25;q++) a2[q]=bv;
    for (int qq=0; qq<50; qq++){
      float hvv = bufA[qq*128 + j];
      #pragma unroll
      for (int q=0;q<25;q++) a2[q] += adj[(nh*25+q)*50 + qq]*hvv;
    }
    __syncthreads();
    #pragma unroll
    for (int q=0;q<25;q++) bufB[(nh*25+q)*128 + j] = lrelu(a2[q]);
  }
  __syncthreads();
  {
    float a2[25];
    #pragma unroll
    for (int q=0;q<25;q++) a2[q]=0.f;
    for (int i=0;i<128;i+=4){
      float w0 = Wc2[(long)(i+0)*128 + j];
      float w1 = Wc2[(long)(i+1)*128 + j];
      float w2 = Wc2[(long)(i+2)*128 + j];
      float w3 = Wc2[(long)(i+3)*128 + j];
      #pragma unroll
      for (int q=0;q<25;q++){
        float4 xv = *(const float4*)&bufB[(nh*25+q)*128 + i];
        a2[q] += xv.x*w0 + xv.y*w1 + xv.z*w2 + xv.w*w3;
      }
    }
    __syncthreads();
    #pragma unroll
    for (int q=0;q<25;q++) bufA[(nh*25+q)*128 + j] = a2[q];
  }
  __syncthreads();
  {
    float a2[25];
    float bv = bc2[j];
    #pragma unroll
    for (int q=0;q<25;q++) a2[q]=bv;
    for (int qq=0; qq<50; qq++){
      float hvv = bufA[qq*128 + j];
      #pragma unroll
      for (int q=0;q<25;q++) a2[q] += adj[(nh*25+q)*50 + qq]*hvv;
    }
    __syncthreads();
    #pragma unroll
    for (int q=0;q<25;q++) bufB[(nh*25+q)*128 + j] = lrelu(a2[q]);
  }
  __syncthreads();
  if (tid < 128){
    float s = 0.f;
    for (int n=0;n<50;n++) s += bufB[n*128 + tid];
    xm[tid] = s * (1.f/50.f);
  }
  __syncthreads();
  if (tid < 64){
    float s = bf1[tid];
    for (int i=0;i<128;i++) s += xm[i]*Wf1[i*64 + tid];
    hv1[tid] = lrelu(s);
  }
  __syncthreads();
  if (tid < 80){
    float s = bf2[tid];
    for (int i=0;i<64;i++) s += hv1[i]*Wf2[i*80 + tid];
    raw[tid] = s;
  }
  __syncthreads();
  if (tid < 4){
    float c = 0.f;
    for (int k=0;k<20;k++){
      c += raw[k*4 + tid];
      hypg[b*80 + k*4 + tid] = maxp[tid] / (1.f + expf(-c));
    }
  }
}

// ---------------- grid barrier: private-flag arrive + single checker + broadcast release ----------------
__device__ __forceinline__ void gbar(unsigned int* done, unsigned int* rel, int k, int bid){
  __syncthreads();
  if (threadIdx.x == 0){
    __threadfence();
    __hip_atomic_store(&done[k*800 + bid], 1u, __ATOMIC_RELEASE, __HIP_MEMORY_SCOPE_AGENT);
  }
  if (bid == 0){
    for (;;){
      int mine = 1;
      for (int i = threadIdx.x; i < 800; i += 256)
        mine &= (int)(__hip_atomic_load(&done[k*800 + i], __ATOMIC_RELAXED, __HIP_MEMORY_SCOPE_AGENT) != 0u);
      if (__syncthreads_and(mine)) break;
      __builtin_amdgcn_s_sleep(4);
    }
    if (threadIdx.x == 0){
      __threadfence();
      __hip_atomic_store(&rel[k], 1u, __ATOMIC_RELEASE, __HIP_MEMORY_SCOPE_AGENT);
    }
  }
  if (threadIdx.x == 0){
    while (__hip_atomic_load(&rel[k], __ATOMIC_RELAXED, __HIP_MEMORY_SCOPE_AGENT) == 0u)
      __builtin_amdgcn_s_sleep(4);
    __threadfence();
  }
  __syncthreads();
}

// ---------------- persistent scan: 800 blocks (p, 64-n slice), y & w in registers ----------------
__global__ __launch_bounds__(256, 4) void k_scan2(
      const unsigned short* __restrict__ ata, const float* __restrict__ atb_g,
      const float* __restrict__ y0, const float* __restrict__ u0,
      const float* __restrict__ d0, const float* __restrict__ dmg,
      const float* __restrict__ snbg, const float* __restrict__ hypg,
      unsigned short* __restrict__ yb0, unsigned short* __restrict__ yb1,
      float* __restrict__ yout, unsigned int* __restrict__ done,
      unsigned int* __restrict__ rel){
  const int bid = blockIdx.x;
  const int p  = bid >> 4;        // 0..49
  const int nt = bid & 15;        // 0..15
  const int tid = threadIdx.x, wave = tid>>6, lane = tid&63;
  const int lr = lane&15, kg = lane>>4;
  const int n  = nt*64 + wave*16 + lr;   // this thread's n column
  __shared__ unsigned short ylds[16][1032];
  __shared__ float dmp[16][52];
  __shared__ float snp[16];
  for (int e = tid; e < 800; e += 256){
    int b = e/50, q = e%50;
    dmp[b][q] = dmg[b*2500 + p*50 + q];
  }
  if (tid < 16) snp[tid] = snbg[tid*NP + p];

  float yv[4], wv[4], dlt[4];
  #pragma unroll
  for (int r=0;r<4;r++){
    const int b = kg*4+r;
    const long idx = ((long)b*NP + p)*NN + n;
    yv[r] = y0[idx];
    wv[r] = u0[idx]*snbg[b*NP + p] - atb_g[idx];
    yb0[idx] = f2bf(yv[r]);
  }
  gbar(done, rel, 0, bid);     // ybf0 ready everywhere; dmp/snp also ready

  for (int k=0;k<NK;k++){
    const unsigned short* ybin = (k&1) ? yb1 : yb0;
    unsigned short*       ybot = (k&1) ? yb0 : yb1;
    // --- dlt = Dm @ y_k at this (b,n); w update ---
    if (k == 0){
      #pragma unroll
      for (int r=0;r<4;r++)
        dlt[r] = d0[((long)(kg*4+r)*NP + p)*NN + n];
    } else {
      #pragma unroll
      for (int r=0;r<4;r++) dlt[r] = 0.f;
      for (int q=0;q<NP;q++){
        #pragma unroll
        for (int r=0;r<4;r++){
          float yq = bfu(ybin[((long)(kg*4+r)*NP + q)*NN + n]);
          dlt[r] += dmp[kg*4+r][q]*yq;
        }
      }
      #pragma unroll
      for (int r=0;r<4;r++)
        wv[r] += dlt[r] * hypg[(kg*4+r)*80 + (k-1)*4 + 3] * snp[kg*4+r];
    }
    // --- stage own-p y_k rows into LDS ---
    __syncthreads();
    {
      int bb = tid>>4, c0 = (tid&15)*8;
      const unsigned short* yr = ybin + ((long)bb*NP + p)*NN;
      #pragma unroll
      for (int it=0; it<8; it++)
        *(uint4*)&ylds[bb][it*128 + c0] = *(const uint4*)(yr + it*128 + c0);
    }
    __syncthreads();
    // --- MFMA: z tile (16 n, 16 b), K = 1024, tiled ata ---
    const unsigned short* bp = ata + ((long)p<<20) + (long)(nt*4 + wave)*16384 + lr*32 + kg*8;
    const unsigned short* yp = &ylds[lr][kg*8];
    f32x4 a0={0.f,0.f,0.f,0.f}, a1={0.f,0.f,0.f,0.f}, a2={0.f,0.f,0.f,0.f}, a3={0.f,0.f,0.f,0.f};
    #pragma unroll 2
    for (int i=0;i<8;i++){
      bf16x8 b0 = *(const bf16x8*)(bp + (i*4+0)*512);
      bf16x8 b1 = *(const bf16x8*)(bp + (i*4+1)*512);
      bf16x8 b2 = *(const bf16x8*)(bp + (i*4+2)*512);
      bf16x8 b3 = *(const bf16x8*)(bp + (i*4+3)*512);
      bf16x8 q0 = *(const bf16x8*)(yp + (i*4+0)*32);
      bf16x8 q1 = *(const bf16x8*)(yp + (i*4+1)*32);
      bf16x8 q2 = *(const bf16x8*)(yp + (i*4+2)*32);
      bf16x8 q3 = *(const bf16x8*)(yp + (i*4+3)*32);
      a0 = __builtin_amdgcn_mfma_f32_16x16x32_bf16(q0, b0, a0, 0,0,0);
      a1 = __builtin_amdgcn_mfma_f32_16x16x32_bf16(q1, b1, a1, 0,0,0);
      a2 = __builtin_amdgcn_mfma_f32_16x16x32_bf16(q2, b2, a2, 0,0,0);
      a3 = __builtin_amdgcn_mfma_f32_16x16x32_bf16(q3, b3, a3, 0,0,0);
    }
    f32x4 z = (a0 + a1) + (a2 + a3);
    // --- y update + outputs ---
    #pragma unroll
    for (int r=0;r<4;r++){
      const int b = kg*4+r;
      const float4 hp = *(const float4*)(hypg + b*80 + k*4);   // alpha,tau,rho,eta
      float e = wv[r] + dlt[r]*hp.z;
      float g = z[r] + ((yv[r]>0.f)?1.f:((yv[r]<0.f)?-1.f:0.f))*hp.y + e;
      yv[r] -= hp.x*g;
      const long idx = ((long)b*NP+p)*NN + n;
      yout[(long)k*YSZ + idx] = yv[r];
      if (k < NK-1) ybot[idx] = f2bf(yv[r]);
    }
    if (k < NK-1) gbar(done, rel, k+1, bid);
  }
}

extern "C" void kernel_launch(void* const* d_in, const int* in_sizes, int n_in,
                              void* d_out, int out_size, void* d_ws, size_t ws_size,
                              hipStream_t stream){
  (void)in_sizes; (void)n_in; (void)out_size; (void)ws_size;
  const float* bin = (const float*)d_in[0];
  const float* A   = (const float*)d_in[1];
  const int*   ei  = (const int*)d_in[2];
  const float* mxp = (const float*)d_in[3];
  const float* We1 = (const float*)d_in[4];  const float* be1 = (const float*)d_in[5];
  const float* We2 = (const float*)d_in[6];  const float* be2 = (const float*)d_in[7];
  const float* We3 = (const float*)d_in[8];  const float* be3 = (const float*)d_in[9];
  const float* Wc1 = (const float*)d_in[10]; const float* bc1 = (const float*)d_in[11];
  const float* Wc2 = (const float*)d_in[12]; const float* bc2 = (const float*)d_in[13];
  const float* Wf1 = (const float*)d_in[14]; const float* bf1 = (const float*)d_in[15];
  const float* Wf2 = (const float*)d_in[16]; const float* bf2 = (const float*)d_in[17];
  const float* y0  = (const float*)d_in[18];
  const float* u0  = (const float*)d_in[19];
  const float* dd0 = (const float*)d_in[20];
  float* out = (float*)d_out;

  char* cur = (char*)d_ws;
  auto alloc = [&](size_t bytes)->void*{
    void* pp = (void*)cur; cur += (bytes + 255) & ~(size_t)255; return pp;
  };
  unsigned short* abfT = (unsigned short*)alloc(ASZ*2);              // 52.4 MB
  unsigned short* ata  = (unsigned short*)alloc((size_t)NP*1024*1024*2);  // 104.9 MB (tiled)
  float* atb = (float*)alloc(YSZ*4);
  unsigned short* ybf0 = (unsigned short*)alloc(YSZ*2);
  unsigned short* ybf1 = (unsigned short*)alloc(YSZ*2);
  float* h1  = (float*)alloc((size_t)16*3200*4);
  float* h2  = (float*)alloc((size_t)16*6400*4);
  float* h3  = (float*)alloc((size_t)16*12800*4);
  float* adj = (float*)alloc((size_t)16*2500*4);
  float* dm  = (float*)alloc((size_t)16*2500*4);
  float* snb = (float*)alloc((size_t)16*50*4);
  float* hyp = (float*)alloc((size_t)16*80*4);
  unsigned int* done = (unsigned int*)alloc((size_t)NK*800*4);   // 64 KB
  unsigned int* rel  = (unsigned int*)alloc((size_t)NK*4);
  float* part= (float*)alloc((size_t)84000000);   // max 100*16*12800*4 = 81.9 MB

  // ---- one-time prep ----
  k_zero<<<dim3(64), dim3(256), 0, stream>>>(done, NK*800);
  k_zero<<<dim3(1),  dim3(256), 0, stream>>>(rel, NK);
  k_prep<<<dim3(50,8,16), dim3(256), 0, stream>>>(A, abfT);
  k_atb<<<dim3(50,8), dim3(256), 0, stream>>>(abfT, bin, atb);
  k_ata<<<dim3(36,50), dim3(256), 0, stream>>>(abfT, ata);

  // ---- encoder MLP ----
  k_enc2<<<dim3(4,200),  dim3(256), 0, stream>>>(bin, We1, part, 25600, 3200, 128, 0);
  k_enc_reduce<<<dim3(200), dim3(256), 0, stream>>>(part, be1, h1, 3200, 200);
  k_enc2<<<dim3(7,50),  dim3(256), 0, stream>>>(h1, We2, part, 3200, 6400, 64, 1);
  k_enc_reduce<<<dim3(400), dim3(256), 0, stream>>>(part, be2, h2, 6400, 50);
  k_enc2<<<dim3(13,100), dim3(256), 0, stream>>>(h2, We3, part, 6400, 12800, 64, 1);
  k_enc_reduce<<<dim3(800), dim3(256), 0, stream>>>(part, be3, h3, 12800, 100);

  // ---- graph + fused GNN/head ----
  k_graph<<<dim3(16), dim3(64), 0, stream>>>(ei, adj, dm, snb);
  k_gnn<<<dim3(16), dim3(256), 0, stream>>>(h3, Wc1, bc1, Wc2, bc2, Wf1, bf1, Wf2, bf2, mxp, adj, hyp);

  // ---- persistent scan: ONE dispatch for all 20 steps ----
  k_scan2<<<dim3(800), dim3(256), 0, stream>>>(ata, atb, y0, u0, dd0, dm, snb, hyp,
                                               ybf0, ybf1, out, done, rel);
}

// Round 14
// 1359.196 us; speedup vs baseline: 1.9677x; 1.5656x over previous
//
#include <hip/hip_runtime.h>

namespace {
constexpr int NB = 16;    // batch
constexpr int NP = 50;    // P nodes
constexpr int NM = 512;   // M
constexpr int NN = 1024;  // N
constexpr int NK = 20;    // scan steps
constexpr long ASZ = (long)NP * NM * NN;   // 26,214,400
constexpr long YSZ = (long)NB * NP * NN;   // 819,200
}

typedef __attribute__((ext_vector_type(8))) short bf16x8;
typedef __attribute__((ext_vector_type(4))) float f32x4;

__device__ __forceinline__ float lrelu(float x){ return x > 0.f ? x : 0.01f*x; }
__device__ __forceinline__ float bfu(unsigned short x){
  unsigned v = ((unsigned)x) << 16;
  return __builtin_bit_cast(float, v);
}
__device__ __forceinline__ unsigned short f2bf(float f){   // RNE f32->bf16
  unsigned u = __builtin_bit_cast(unsigned, f);
  u += 0x7fffu + ((u >> 16) & 1u);
  return (unsigned short)(u >> 16);
}
// tiled AtA element offset: [ntile=n>>4][ks=k>>5][lr=n&15][kg=(k>>3)&3][e=k&7]
__device__ __forceinline__ long toff(int n, int kk){
  return (long)(n>>4)*16384 + (long)(kk>>5)*512 + (long)((n&15)*32 + ((kk>>3)&3)*8 + (kk&7));
}

// ---------------- A (f32) -> abfT (transposed bf16 [p][n][m]) ----------------
__global__ __launch_bounds__(256) void k_prep(const float* __restrict__ A,
                      unsigned short* __restrict__ abfT){
  const int p = blockIdx.x, mt = blockIdx.y, nt = blockIdx.z;
  const int tid = threadIdx.x;
  __shared__ unsigned short tile[64][72];
  const int m0 = mt*64, n0 = nt*64;
  {
    int r = tid>>2, cs = (tid&3)*16;
    const float* src = A + ((long)p*NM + m0 + r)*NN + n0 + cs;
    unsigned short tmp[16];
    #pragma unroll
    for (int q=0;q<16;q+=4){
      float4 v = *(const float4*)(src+q);
      tmp[q+0]=f2bf(v.x); tmp[q+1]=f2bf(v.y); tmp[q+2]=f2bf(v.z); tmp[q+3]=f2bf(v.w);
    }
    #pragma unroll
    for (int q=0;q<16;q++) tile[r][cs+q] = tmp[q];
  }
  __syncthreads();
  {
    int r = tid>>2, cs = (tid&3)*16;   // r = n-offset, cs = m-offset
    unsigned short* dst = abfT + ((long)p*NN + n0 + r)*NM + m0 + cs;
    unsigned short tmp[16];
    #pragma unroll
    for (int q=0;q<16;q++) tmp[q] = tile[cs+q][r];
    #pragma unroll
    for (int q=0;q<16;q+=8) *(uint4*)(dst+q) = *(const uint4*)&tmp[q];
  }
}

// ---------------- scan-state init: y, ybf ----------------
__global__ void k_init(const float* __restrict__ y0, float* __restrict__ y,
                       unsigned short* __restrict__ ybf, int n){
  int e = (blockIdx.x*blockDim.x + threadIdx.x)*4;
  if (e >= n) return;
  float4 a = *(const float4*)(y0+e);
  *(float4*)(y+e) = a;
  ushort4 o; o.x=f2bf(a.x); o.y=f2bf(a.y); o.z=f2bf(a.z); o.w=f2bf(a.w);
  *(ushort4*)(ybf+e) = o;
}

// ---------------- w0 = u0*snb - atb ; e0 = w0 + d0*rho_0 ----------------
__global__ __launch_bounds__(256) void k_e0(const float* __restrict__ u0,
      const float* __restrict__ d0, const float* __restrict__ atb,
      const float* __restrict__ snbg, const float* __restrict__ hypg,
      float* __restrict__ w, float* __restrict__ e){
  long i = ((long)blockIdx.x*256 + threadIdx.x)*4;
  if (i >= YSZ) return;
  long bp = i >> 10;          // b*NP+p
  int b = (int)(bp/NP), p = (int)(bp%NP);
  float sp = snbg[b*NP+p], rho = hypg[b*80 + 2];
  float4 uv = *(const float4*)(u0+i);
  float4 dv = *(const float4*)(d0+i);
  float4 av = *(const float4*)(atb+i);
  float4 wv, ev;
  wv.x = uv.x*sp - av.x; wv.y = uv.y*sp - av.y;
  wv.z = uv.z*sp - av.z; wv.w = uv.w*sp - av.w;
  ev.x = wv.x + dv.x*rho; ev.y = wv.y + dv.y*rho;
  ev.z = wv.z + dv.z*rho; ev.w = wv.w + dv.w*rho;
  *(float4*)(w+i) = wv;
  *(float4*)(e+i) = ev;
}

// ================= role bodies (shared by merged kernel) =================

// ---- encoder GEMM body: float4 W stream, acc[16] float4 ----
__device__ __forceinline__ void enc_body(const float* __restrict__ X, const float* __restrict__ W,
                           float* __restrict__ part, int fi, int fo, int ichunk, int actin,
                           int bx, int c, int tid, char* smem){
  float (*xs)[16] = (float(*)[16])smem;   // [64][16]
  const int o0 = (bx*256 + tid)*4;
  const bool ok = o0 < fo;   // fo multiple of 4
  float4 acc[16];
  #pragma unroll
  for (int b=0;b<16;b++){ acc[b].x=0.f; acc[b].y=0.f; acc[b].z=0.f; acc[b].w=0.f; }
  const long ibase = (long)c*ichunk;
  const int xb = tid&15, xio = (tid>>4)*4;
  for (int s=0; s<ichunk; s+=64){
    float4 v = *(const float4*)(X + (long)xb*fi + ibase + s + xio);
    if (actin){ v.x=lrelu(v.x); v.y=lrelu(v.y); v.z=lrelu(v.z); v.w=lrelu(v.w); }
    __syncthreads();
    xs[xio+0][xb]=v.x; xs[xio+1][xb]=v.y; xs[xio+2][xb]=v.z; xs[xio+3][xb]=v.w;
    __syncthreads();
    const float* wp = W + (ibase+s)*fo + o0;
    #pragma unroll 4
    for (int i=0;i<64;i++){
      float4 w;
      if (ok) w = *(const float4*)(wp + (long)i*fo);
      else { w.x=0.f; w.y=0.f; w.z=0.f; w.w=0.f; }
      #pragma unroll
      for (int b2=0;b2<16;b2+=4){
        float4 x4 = *(const float4*)&xs[i][b2];
        acc[b2+0].x += w.x*x4.x; acc[b2+0].y += w.y*x4.x; acc[b2+0].z += w.z*x4.x; acc[b2+0].w += w.w*x4.x;
        acc[b2+1].x += w.x*x4.y; acc[b2+1].y += w.y*x4.y; acc[b2+1].z += w.z*x4.y; acc[b2+1].w += w.w*x4.y;
        acc[b2+2].x += w.x*x4.z; acc[b2+2].y += w.y*x4.z; acc[b2+2].z += w.z*x4.z; acc[b2+2].w += w.w*x4.z;
        acc[b2+3].x += w.x*x4.w; acc[b2+3].y += w.y*x4.w; acc[b2+3].z += w.z*x4.w; acc[b2+3].w += w.w*x4.w;
      }
    }
  }
  if (ok){
    float* pp = part + ((long)c*16)*fo + o0;
    #pragma unroll
    for (int b=0;b<16;b++) *(float4*)(pp + (long)b*fo) = acc[b];
  }
}

// ---- AtA body (tile-pair bi<=bj), bf16 out in TILED layout ----
__device__ __forceinline__ void ata_body(const unsigned short* __restrict__ abfT,
                      unsigned short* __restrict__ ata, int yy_in, int p, int tid, char* smem){
  unsigned short (*pa)[72] = (unsigned short(*)[72])smem;            // [128][72]
  unsigned short (*pb)[72] = (unsigned short(*)[72])(smem + 18432);  // [128][72]
  int yy = yy_in, bi = 0;
  while (yy >= 8 - bi){ yy -= 8 - bi; bi++; }
  const int bj = bi + yy;
  const int i0 = bi*128, j0 = bj*128;
  const int wave = tid>>6, lane = tid&63;
  const int lr = lane&15, kg = lane>>4;
  f32x4 acc[2][8];
  #pragma unroll
  for (int ti=0;ti<2;ti++)
    #pragma unroll
    for (int tj=0;tj<8;tj++) acc[ti][tj] = (f32x4){0.f,0.f,0.f,0.f};
  const unsigned short* Abase = abfT + (long)p*NN*NM;
  for (int mc=0; mc<NM; mc+=64){
    __syncthreads();
    {
      int r = tid>>1, c0 = (tid&1)*32;
      const unsigned short* sa = Abase + (long)(i0 + r)*NM + mc + c0;
      const unsigned short* sb = Abase + (long)(j0 + r)*NM + mc + c0;
      #pragma unroll
      for (int q=0;q<32;q+=8){
        *(uint4*)&pa[r][c0+q] = *(const uint4*)(sa+q);
        *(uint4*)&pb[r][c0+q] = *(const uint4*)(sb+q);
      }
    }
    __syncthreads();
    #pragma unroll
    for (int ks=0; ks<2; ks++){
      bf16x8 av0 = *(const bf16x8*)&pa[wave*32      + lr][ks*32 + kg*8];
      bf16x8 av1 = *(const bf16x8*)&pa[wave*32 + 16 + lr][ks*32 + kg*8];
      #pragma unroll
      for (int tj=0;tj<8;tj++){
        bf16x8 bv = *(const bf16x8*)&pb[tj*16 + lr][ks*32 + kg*8];
        acc[0][tj] = __builtin_amdgcn_mfma_f32_16x16x32_bf16(av0, bv, acc[0][tj], 0,0,0);
        acc[1][tj] = __builtin_amdgcn_mfma_f32_16x16x32_bf16(av1, bv, acc[1][tj], 0,0,0);
      }
    }
  }
  const long pbase = (long)p << 20;
  #pragma unroll
  for (int ti=0; ti<2; ti++){
    const int ib = i0 + wave*32 + ti*16;
    #pragma unroll
    for (int tj=0; tj<8; tj++){
      const int jb = j0 + tj*16;
      unsigned short w[4];
      #pragma unroll
      for (int r=0;r<4;r++) w[r] = f2bf(acc[ti][tj][r]);
      #pragma unroll
      for (int r=0;r<4;r++)
        ata[pbase + toff(ib + kg*4 + r, jb + lr)] = w[r];
      if (bi != bj){
        #pragma unroll
        for (int r=0;r<4;r++)
          ata[pbase + toff(jb + lr, ib + kg*4 + r)] = w[r];
      }
    }
  }
}

// ---- Atb body: atb[b,p,n] = sum_m A[p,m,n]*b[b,p,m] (f32 src) ----
__device__ __forceinline__ void atb_body(const unsigned short* __restrict__ abfT,
                      const float* __restrict__ src, float* __restrict__ z,
                      int p, int gy, int tid, char* smem){
  unsigned short (*tlds)[520] = (unsigned short(*)[520])smem;   // [16][520]
  const int wave = tid>>6, lane = tid&63;
  {
    int b = tid>>4, c0 = (tid&15)*8;
    const float* tr = src + ((long)b*NP + p)*NM;
    #pragma unroll
    for (int it=0; it<4; it++){
      float4 lo = *(const float4*)(tr + it*128 + c0);
      float4 hi = *(const float4*)(tr + it*128 + c0 + 4);
      unsigned short w[8];
      w[0]=f2bf(lo.x); w[1]=f2bf(lo.y); w[2]=f2bf(lo.z); w[3]=f2bf(lo.w);
      w[4]=f2bf(hi.x); w[5]=f2bf(hi.y); w[6]=f2bf(hi.z); w[7]=f2bf(hi.w);
      *(uint4*)&tlds[b][it*128 + c0] = *(const uint4*)w;
    }
  }
  __syncthreads();
  const int lr = lane&15, kg = lane>>4;
  const int nt0 = gy*4 + wave;
  const int n0 = nt0*16, n1 = (nt0+32)*16;
  const unsigned short* b0 = abfT + ((long)p*NN + n0 + lr)*NM + kg*8;
  const unsigned short* b1 = abfT + ((long)p*NN + n1 + lr)*NM + kg*8;
  const unsigned short* tp = &tlds[lr][kg*8];
  f32x4 acc0a={0.f,0.f,0.f,0.f}, acc0b={0.f,0.f,0.f,0.f};
  f32x4 acc1a={0.f,0.f,0.f,0.f}, acc1b={0.f,0.f,0.f,0.f};
  #pragma unroll 4
  for (int ks=0; ks<16; ks+=2){
    bf16x8 t0 = *(const bf16x8*)(tp + ks*32);
    bf16x8 t1 = *(const bf16x8*)(tp + ks*32 + 32);
    bf16x8 b00 = *(const bf16x8*)(b0 + (long)ks*32);
    bf16x8 b01 = *(const bf16x8*)(b0 + (long)ks*32 + 32);
    bf16x8 b10 = *(const bf16x8*)(b1 + (long)ks*32);
    bf16x8 b11 = *(const bf16x8*)(b1 + (long)ks*32 + 32);
    acc0a = __builtin_amdgcn_mfma_f32_16x16x32_bf16(t0, b00, acc0a, 0, 0, 0);
    acc1a = __builtin_amdgcn_mfma_f32_16x16x32_bf16(t0, b10, acc1a, 0, 0, 0);
    acc0b = __builtin_amdgcn_mfma_f32_16x16x32_bf16(t1, b01, acc0b, 0, 0, 0);
    acc1b = __builtin_amdgcn_mfma_f32_16x16x32_bf16(t1, b11, acc1b, 0, 0, 0);
  }
  f32x4 acc0 = acc0a + acc0b;
  f32x4 acc1 = acc1a + acc1b;
  #pragma unroll
  for (int r=0;r<4;r++){
    int bb = kg*4 + r;
    z[((long)bb*NP + p)*NN + n0 + lr] = acc0[r];
    z[((long)bb*NP + p)*NN + n1 + lr] = acc1[r];
  }
}

// ---------------- merged: enc-L1 (800) ∥ AtA (1800) ∥ Atb (400) ----------------
__global__ __launch_bounds__(256) void k_big(const unsigned short* __restrict__ abfT,
      unsigned short* __restrict__ ata, const float* __restrict__ bin,
      const float* __restrict__ We1, float* __restrict__ part,
      float* __restrict__ atb){
  __shared__ __align__(16) char smem[36864];
  const int bid = blockIdx.x, tid = threadIdx.x;
  if (bid < 800){
    enc_body(bin, We1, part, 25600, 3200, 128, 0, bid & 3, bid >> 2, tid, smem);
  } else if (bid < 2600){
    int a = bid - 800;
    ata_body(abfT, ata, a % 36, a / 36, tid, smem);
  } else {
    int a = bid - 2600;
    atb_body(abfT, bin, atb, a >> 3, a & 7, tid, smem);
  }
}

// ---------------- standalone encoder GEMM (L2/L3) ----------------
__global__ __launch_bounds__(256) void k_enc2(const float* __restrict__ X, const float* __restrict__ W,
                           float* __restrict__ part, int fi, int fo, int ichunk, int actin){
  __shared__ __align__(16) char smem[4096];
  enc_body(X, W, part, fi, fo, ichunk, actin, blockIdx.x, blockIdx.y, threadIdx.x, smem);
}

__global__ void k_enc_reduce(const float* __restrict__ part, const float* __restrict__ bias,
                             float* __restrict__ out, int fo, int nchunk){
  int i = blockIdx.x*256 + threadIdx.x;
  if (i >= 16*fo) return;
  int o = i % fo;
  float s = bias[o];
  for (int c=0;c<nchunk;c++) s += part[(long)c*16*fo + i];
  out[i] = s;
}

// ---------------- per-batch graph matrices ----------------
__global__ __launch_bounds__(64) void k_graph(const int* __restrict__ ei, float* __restrict__ adjg,
                        float* __restrict__ dmg, float* __restrict__ snbg){
  const int b = blockIdx.x, tid = threadIdx.x;
  __shared__ float adj[2500], dm[2500], deg[50], dinv[50], snb[50];
  for (int i=tid;i<2500;i+=64){ adj[i]=0.f; dm[i]=0.f; }
  if (tid<50){ deg[tid]=0.f; snb[tid]=0.f; }
  __syncthreads();
  const int* e = ei + b*800;
  for (int k=tid;k<400;k+=64){
    atomicAdd(&deg[e[400+k]], 1.f);
    atomicAdd(&snb[e[k]], 1.f);
  }
  __syncthreads();
  if (tid<50) dinv[tid] = 1.f / sqrtf(deg[tid] + 1.f);
  __syncthreads();
  for (int k=tid;k<400;k+=64){
    int s = e[k], d = e[400+k];
    atomicAdd(&adj[d*50+s], dinv[s]*dinv[d]);
    atomicAdd(&dm[s*50+s],  1.f); atomicAdd(&dm[s*50+d], -1.f);
    atomicAdd(&dm[d*50+d],  1.f); atomicAdd(&dm[d*50+s], -1.f);
  }
  __syncthreads();
  if (tid<50) adj[tid*50+tid] += dinv[tid]*dinv[tid];
  __syncthreads();
  for (int i=tid;i<2500;i+=64){ adjg[b*2500+i]=adj[i]; dmg[b*2500+i]=dm[i]; }
  if (tid<50) snbg[b*50+tid]=snb[tid];
}

// ---------------- fused GCN x2 + head ----------------
__global__ __launch_bounds__(256) void k_gnn(const float* __restrict__ h3,
     const float* __restrict__ Wc1, const float* __restrict__ bc1,
     const float* __restrict__ Wc2, const float* __restrict__ bc2,
     const float* __restrict__ Wf1, const float* __restrict__ bf1,
     const float* __restrict__ Wf2, const float* __restrict__ bf2,
     const float* __restrict__ maxp, const float* __restrict__ adjg,
     float* __restrict__ hypg){
  const int b = blockIdx.x, tid = threadIdx.x;
  __shared__ float adj[2500];
  __shared__ float bufA[6400];
  __shared__ float bufB[6400];
  __shared__ float xm[128], hv1[64], raw[80];
  for (int i=tid;i<2500;i+=256) adj[i] = adjg[b*2500+i];

  const int j = tid & 127, nh = tid >> 7;
  float acc[25];
  #pragma unroll
  for (int q=0;q<25;q++) acc[q]=0.f;
  for (int ic=0; ic<4; ic++){
    __syncthreads();
    for (int e=tid; e<800; e+=256){
      int n = e>>4, seg = (e&15)*4;
      *(float4*)&bufB[n*64+seg] = *(const float4*)(h3 + (long)b*12800 + n*256 + ic*64 + seg);
    }
    __syncthreads();
    for (int i=0;i<64;i+=4){
      float w0 = Wc1[(long)(ic*64+i+0)*128 + j];
      float w1 = Wc1[(long)(ic*64+i+1)*128 + j];
      float w2 = Wc1[(long)(ic*64+i+2)*128 + j];
      float w3 = Wc1[(long)(ic*64+i+3)*128 + j];
      #pragma unroll
      for (int q=0;q<25;q++){
        float4 xv = *(const float4*)&bufB[(nh*25+q)*64 + i];
        acc[q] += xv.x*w0 + xv.y*w1 + xv.z*w2 + xv.w*w3;
      }
    }
  }
  __syncthreads();
  #pragma unroll
  for (int q=0;q<25;q++) bufA[(nh*25+q)*128 + j] = acc[q];
  __syncthreads();
  {
    float a2[25];
    float bv = bc1[j];
    #pragma unroll
    for (int q=0;q<25;q++) a2[q]=bv;
    for (int qq=0; qq<50; qq++){
      float hvv = bufA[qq*128 + j];
      #pragma unroll
      for (int q=0;q<25;q++) a2[q] += adj[(nh*25+q)*50 + qq]*hvv;
    }
    __syncthreads();
    #pragma unroll
    for (int q=0;q<25;q++) bufB[(nh*25+q)*128 + j] = lrelu(a2[q]);
  }
  __syncthreads();
  {
    float a2[25];
    #pragma unroll
    for (int q=0;q<25;q++) a2[q]=0.f;
    for (int i=0;i<128;i+=4){
      float w0 = Wc2[(long)(i+0)*128 + j];
      float w1 = Wc2[(long)(i+1)*128 + j];
      float w2 = Wc2[(long)(i+2)*128 + j];
      float w3 = Wc2[(long)(i+3)*128 + j];
      #pragma unroll
      for (int q=0;q<25;q++){
        float4 xv = *(const float4*)&bufB[(nh*25+q)*128 + i];
        a2[q] += xv.x*w0 + xv.y*w1 + xv.z*w2 + xv.w*w3;
      }
    }
    __syncthreads();
    #pragma unroll
    for (int q=0;q<25;q++) bufA[(nh*25+q)*128 + j] = a2[q];
  }
  __syncthreads();
  {
    float a2[25];
    float bv = bc2[j];
    #pragma unroll
    for (int q=0;q<25;q++) a2[q]=bv;
    for (int qq=0; qq<50; qq++){
      float hvv = bufA[qq*128 + j];
      #pragma unroll
      for (int q=0;q<25;q++) a2[q] += adj[(nh*25+q)*50 + qq]*hvv;
    }
    __syncthreads();
    #pragma unroll
    for (int q=0;q<25;q++) bufB[(nh*25+q)*128 + j] = lrelu(a2[q]);
  }
  __syncthreads();
  if (tid < 128){
    float s = 0.f;
    for (int n=0;n<50;n++) s += bufB[n*128 + tid];
    xm[tid] = s * (1.f/50.f);
  }
  __syncthreads();
  if (tid < 64){
    float s = bf1[tid];
    for (int i=0;i<128;i++) s += xm[i]*Wf1[i*64 + tid];
    hv1[tid] = lrelu(s);
  }
  __syncthreads();
  if (tid < 80){
    float s = bf2[tid];
    for (int i=0;i<64;i++) s += hv1[i]*Wf2[i*80 + tid];
    raw[tid] = s;
  }
  __syncthreads();
  if (tid < 4){
    float c = 0.f;
    for (int k=0;k<20;k++){
      c += raw[k*4 + tid];
      hypg[b*80 + k*4 + tid] = maxp[tid] / (1.f + expf(-c));
    }
  }
}

// ---------------- scan: z = AtA[p] @ y + fused y-update (tiled AtA) ----------------
__global__ __launch_bounds__(256, 4) void k_z(const unsigned short* __restrict__ ata,
      const unsigned short* __restrict__ ybin, const float* __restrict__ ebuf,
      const float* __restrict__ hypg, int k,
      float* __restrict__ y, unsigned short* __restrict__ ybout,
      float* __restrict__ yout){
  const int p = blockIdx.x;
  const int tid = threadIdx.x, wave = tid>>6, lane = tid&63;
  __shared__ unsigned short ylds[16][1032];
  {
    int b = tid>>4, c0 = (tid&15)*8;
    const unsigned short* yr = ybin + ((long)b*NP + p)*NN;
    #pragma unroll
    for (int it=0; it<8; it++)
      *(uint4*)&ylds[b][it*128 + c0] = *(const uint4*)(yr + it*128 + c0);
  }
  const int lr = lane&15, kg = lane>>4;
  const int t  = blockIdx.y*4 + wave;           // n-tile 0..63
  const int n0 = t*16;
  const unsigned short* bp = ata + ((long)p<<20) + (long)t*16384 + lr*32 + kg*8;
  const unsigned short* yp = &ylds[lr][kg*8];

  bf16x8 B[3][4];
  #pragma unroll
  for (int j=0;j<4;j++) B[0][j] = *(const bf16x8*)(bp + (0*4+j)*512);
  #pragma unroll
  for (int j=0;j<4;j++) B[1][j] = *(const bf16x8*)(bp + (1*4+j)*512);

  float yv4[4], e4[4];
  float4 hp4[4];
  #pragma unroll
  for (int r=0;r<4;r++){
    const int b = kg*4 + r;
    const long idx = ((long)b*NP + p)*NN + n0 + lr;
    yv4[r] = y[idx]; e4[r] = ebuf[idx];
    hp4[r] = *(const float4*)(hypg + b*80 + k*4);
  }
  __syncthreads();

  f32x4 a0={0.f,0.f,0.f,0.f}, a1={0.f,0.f,0.f,0.f}, a2={0.f,0.f,0.f,0.f}, a3={0.f,0.f,0.f,0.f};
  #pragma unroll
  for (int i=0;i<8;i++){
    const int cur = i % 3;
    const int nxt = (i+2) % 3;
    if (i < 6){
      #pragma unroll
      for (int j=0;j<4;j++) B[nxt][j] = *(const bf16x8*)(bp + ((i+2)*4+j)*512);
    }
    bf16x8 q0 = *(const bf16x8*)(yp + (i*4+0)*32);
    bf16x8 q1 = *(const bf16x8*)(yp + (i*4+1)*32);
    bf16x8 q2 = *(const bf16x8*)(yp + (i*4+2)*32);
    bf16x8 q3 = *(const bf16x8*)(yp + (i*4+3)*32);
    a0 = __builtin_amdgcn_mfma_f32_16x16x32_bf16(q0, B[cur][0], a0, 0,0,0);
    a1 = __builtin_amdgcn_mfma_f32_16x16x32_bf16(q1, B[cur][1], a1, 0,0,0);
    a2 = __builtin_amdgcn_mfma_f32_16x16x32_bf16(q2, B[cur][2], a2, 0,0,0);
    a3 = __builtin_amdgcn_mfma_f32_16x16x32_bf16(q3, B[cur][3], a3, 0,0,0);
  }
  f32x4 z = (a0 + a1) + (a2 + a3);
  #pragma unroll
  for (int r=0;r<4;r++){
    const int b = kg*4 + r;
    const long idx = ((long)b*NP + p)*NN + n0 + lr;
    float yv = yv4[r];
    float g = z[r] + ((yv>0.f)?1.f:((yv<0.f)?-1.f:0.f))*hp4[r].y + e4[r];
    float ynv = yv - hp4[r].x*g;
    y[idx] = ynv; ybout[idx] = f2bf(ynv); yout[(long)k*YSZ + idx] = ynv;
  }
}

// ---------------- scan: dl = Dm @ y_{k+1} (bf16) ; w += dl*eta*snb ; e = w + dl*rho_{k+1} ----------------
__global__ __launch_bounds__(256) void k_dm(const float* __restrict__ dmg,
      const float* __restrict__ snbg, const float* __restrict__ hypg, int k,
      const unsigned short* __restrict__ ybf, float* __restrict__ w, float* __restrict__ e){
  const int b = blockIdx.x, n0 = blockIdx.y*64, tid = threadIdx.x;
  __shared__ float ys[50][64];
  __shared__ float dms[2500];
  for (int i=tid;i<2500;i+=256) dms[i] = dmg[b*2500+i];
  for (int i=tid; i<3200; i+=256){
    int p=i>>6, nn=i&63;
    ys[p][nn] = bfu(ybf[((long)b*NP+p)*NN + n0 + nn]);
  }
  __syncthreads();
  const float eta = hypg[b*80 + k*4 + 3];
  const float rhon = hypg[b*80 + (k+1)*4 + 2];
  for (int i=tid; i<3200; i+=256){
    int p=i>>6, nn=i&63;
    float s=0.f;
    #pragma unroll 10
    for (int q=0;q<NP;q++) s += dms[p*50+q]*ys[q][nn];
    long idx = ((long)b*NP+p)*NN + n0 + nn;
    float wn = w[idx] + s*eta*snbg[b*NP+p];
    w[idx] = wn;
    e[idx] = wn + s*rhon;
  }
}

extern "C" void kernel_launch(void* const* d_in, const int* in_sizes, int n_in,
                              void* d_out, int out_size, void* d_ws, size_t ws_size,
                              hipStream_t stream){
  (void)in_sizes; (void)n_in; (void)out_size; (void)ws_size;
  const float* bin = (const float*)d_in[0];
  const float* A   = (const float*)d_in[1];
  const int*   ei  = (const int*)d_in[2];
  const float* mxp = (const float*)d_in[3];
  const float* We1 = (const float*)d_in[4];  const float* be1 = (const float*)d_in[5];
  const float* We2 = (const float*)d_in[6];  const float* be2 = (const float*)d_in[7];
  const float* We3 = (const float*)d_in[8];  const float* be3 = (const float*)d_in[9];
  const float* Wc1 = (const float*)d_in[10]; const float* bc1 = (const float*)d_in[11];
  const float* Wc2 = (const float*)d_in[12]; const float* bc2 = (const float*)d_in[13];
  const float* Wf1 = (const float*)d_in[14]; const float* bf1 = (const float*)d_in[15];
  const float* Wf2 = (const float*)d_in[16]; const float* bf2 = (const float*)d_in[17];
  const float* y0  = (const float*)d_in[18];
  const float* u0  = (const float*)d_in[19];
  const float* dd0 = (const float*)d_in[20];
  float* out = (float*)d_out;

  char* cur = (char*)d_ws;
  auto alloc = [&](size_t bytes)->void*{
    void* pp = (void*)cur; cur += (bytes + 255) & ~(size_t)255; return pp;
  };
  unsigned short* abfT = (unsigned short*)alloc(ASZ*2);              // 52.4 MB
  unsigned short* ata  = (unsigned short*)alloc((size_t)NP*1024*1024*2);  // 104.9 MB (tiled)
  float* atb = (float*)alloc(YSZ*4);
  float* y   = (float*)alloc(YSZ*4);
  unsigned short* ybf0 = (unsigned short*)alloc(YSZ*2);
  unsigned short* ybf1 = (unsigned short*)alloc(YSZ*2);
  float* w   = (float*)alloc(YSZ*4);
  float* eb  = (float*)alloc(YSZ*4);
  float* h1  = (float*)alloc((size_t)16*3200*4);
  float* h2  = (float*)alloc((size_t)16*6400*4);
  float* h3  = (float*)alloc((size_t)16*12800*4);
  float* adj = (float*)alloc((size_t)16*2500*4);
  float* dm  = (float*)alloc((size_t)16*2500*4);
  float* snb = (float*)alloc((size_t)16*50*4);
  float* hyp = (float*)alloc((size_t)16*80*4);
  float* part= (float*)alloc((size_t)84000000);   // max 200*16*3200*4 = 40.9 MB (L1), 81.9 MB (L3)

  // ---- one-time prep ----
  k_prep<<<dim3(50,8,16), dim3(256), 0, stream>>>(A, abfT);
  k_init<<<dim3(800), dim3(256), 0, stream>>>(y0, y, ybf0, (int)YSZ);

  // ---- merged: enc-L1 || AtA || Atb ----
  k_big<<<dim3(3000), dim3(256), 0, stream>>>(abfT, ata, bin, We1, part, atb);
  k_enc_reduce<<<dim3(200), dim3(256), 0, stream>>>(part, be1, h1, 3200, 200);

  // ---- encoder L2/L3 ----
  k_enc2<<<dim3(7,100),  dim3(256), 0, stream>>>(h1, We2, part, 3200, 6400, 32, 1);
  k_enc_reduce<<<dim3(400), dim3(256), 0, stream>>>(part, be2, h2, 6400, 100);
  k_enc2<<<dim3(13,100), dim3(256), 0, stream>>>(h2, We3, part, 6400, 12800, 64, 1);
  k_enc_reduce<<<dim3(800), dim3(256), 0, stream>>>(part, be3, h3, 12800, 100);

  // ---- graph + fused GNN/head ----
  k_graph<<<dim3(16), dim3(64), 0, stream>>>(ei, adj, dm, snb);
  k_gnn<<<dim3(16), dim3(256), 0, stream>>>(h3, Wc1, bc1, Wc2, bc2, Wf1, bf1, Wf2, bf2, mxp, adj, hyp);
  k_e0<<<dim3(800), dim3(256), 0, stream>>>(u0, dd0, atb, snb, hyp, w, eb);

  // ---- scan: 2 kernels/step (k_dm skipped on last step) ----
  for (int k=0;k<NK;k++){
    const unsigned short* ybin = (k & 1) ? ybf1 : ybf0;
    unsigned short* ybout      = (k & 1) ? ybf0 : ybf1;
    k_z<<<dim3(50,16), dim3(256), 0, stream>>>(ata, ybin, eb, hyp, k, y, ybout, out);
    if (k < NK-1){
      const unsigned short* ybnew = (k & 1) ? ybf0 : ybf1;
      k_dm<<<dim3(16,16), dim3(256), 0, stream>>>(dm, snb, hyp, k, ybnew, w, eb);
    }
  }
}